// Round 1
// baseline (175.146 us; speedup 1.0000x reference)
//
#include <hip/hip_runtime.h>
#include <math.h>

// Problem constants (fixed by setup_inputs)
#define NB 32
#define SEQ 512
#define HD 768
#define NL 9
#define NSPAN (NB * 4096)
#define LOGITS_N (NSPAN * NL)     // 1179648
#define RS 156                    // padded LDS row stride for 9x150 tables
#define WRS 152                   // padded row stride for relu'd width table

// ---------------------------------------------------------------------------
// fusedAB: one block per batch, 1024 threads. Replaces stageA+stageB.
// All intermediates live in LDS (95 KB/block, 1 block/CU — fine, grid=32):
//   P0: stage relu(seq rows 0..8) (contiguous 27.6 KB), relu(width_table), W3
//   P1: 900 thr: seq@W1 partials (3 k-chunks of 256);
//       124 thr: width@W1 + b1 rows
//   P2: 900 thr: reduce k-chunk partials -> swl/ewl;
//       124 thr: w23 = W2@W3 (+9 thr: b23 = b2@W3+b3)
//   P3: 729 thr: one combo each -> 9 logits + lse -> global ctab
// Eliminates the part[] global roundtrip (5.5 MB write + 33 MB read) and one
// kernel launch. Loss slot zeroed here (block 0) before stageC's atomics.
// ---------------------------------------------------------------------------
__global__ __launch_bounds__(1024) void fusedAB(
    const float* __restrict__ seq, const float* __restrict__ wtab,
    const float* __restrict__ W1, const float* __restrict__ b1,
    const float* __restrict__ W2, const float* __restrict__ b2,
    const float* __restrict__ W3, const float* __restrict__ b3,
    float* __restrict__ ctab, float* __restrict__ out)
{
  __shared__ __align__(16) float xr[9 * HD];       // 6912 relu'd seq rows
  __shared__ __align__(16) float wrelu[9 * WRS];   // 1368 relu'd width table
  __shared__ __align__(16) float w3l[1350];        // W3 copy
  __shared__ __align__(16) float pbuf[3 * 2700];   // k-chunk partials
  __shared__ __align__(16) float swl[9 * RS];
  __shared__ __align__(16) float ewl[9 * RS];
  __shared__ __align__(16) float wwl[9 * RS];
  __shared__ __align__(16) float w23l[1800];       // (W2@W3)[j][l], stride 12
  __shared__ float b23l[12];

  const int t = threadIdx.x, b = blockIdx.x;
  if (b == 0 && t == 0) out[LOGITS_N] = 0.f;  // loss slot, before stageC adds

  // ---- P0: stage inputs ----
  {
    const float4* s4 = (const float4*)(seq + (size_t)b * SEQ * HD);
    float4* x4 = (float4*)xr;
    for (int i = t; i < 9 * HD / 4; i += 1024) {
      float4 v = s4[i];
      x4[i] = make_float4(fmaxf(v.x, 0.f), fmaxf(v.y, 0.f),
                          fmaxf(v.z, 0.f), fmaxf(v.w, 0.f));
    }
    for (int i = t; i < 1350; i += 1024) {
      int w = i / 150, k = i - 150 * w;
      wrelu[w * WRS + k] = fmaxf(wtab[i], 0.f);
      w3l[i] = W3[i];
    }
  }
  __syncthreads();

  // ---- P1: W1 projections ----
  if (t < 900) {
    // seq part: t = kc*300 + half*150 + j ; k-chunk of 256, acc over 9 s
    const int kc = t / 300, c = t - kc * 300;
    const int half = c / 150, j = c - 150 * half;
    const int k0 = kc * 256;
    const float* w1p = W1 + (size_t)(half * HD + k0) * 150 + j;  // coalesced in j
    float acc[9];
#pragma unroll
    for (int s = 0; s < 9; ++s) acc[s] = 0.f;
    for (int k = 0; k < 256; k += 4) {
      float wv0 = w1p[(size_t)(k + 0) * 150];
      float wv1 = w1p[(size_t)(k + 1) * 150];
      float wv2 = w1p[(size_t)(k + 2) * 150];
      float wv3 = w1p[(size_t)(k + 3) * 150];
      const float* xk = xr + k0 + k;  // wave-uniform -> LDS broadcast reads
#pragma unroll
      for (int s = 0; s < 9; ++s) {
        float4 x = *(const float4*)(xk + s * HD);
        acc[s] = fmaf(x.x, wv0, fmaf(x.y, wv1, fmaf(x.z, wv2, fmaf(x.w, wv3, acc[s]))));
      }
    }
    float* pp = pbuf + t * 9;  // (kc*300+c)*9 == t*9
#pragma unroll
    for (int s = 0; s < 9; ++s) pp[s] = acc[s];
  } else {
    // width part: wwl[w][j] = b1[j] + relu(wtab[w]) . W1[1536+.., j]
    for (int j = t - 900; j < 150; j += 124) {
      const float bb = b1[j];
      float acc[9];
#pragma unroll
      for (int w = 0; w < 9; ++w) acc[w] = bb;
      const float* w1p = W1 + (size_t)1536 * 150 + j;
      for (int k = 0; k < 148; k += 4) {
        float wv0 = w1p[(size_t)(k + 0) * 150];
        float wv1 = w1p[(size_t)(k + 1) * 150];
        float wv2 = w1p[(size_t)(k + 2) * 150];
        float wv3 = w1p[(size_t)(k + 3) * 150];
#pragma unroll
        for (int w = 0; w < 9; ++w) {
          float4 x = *(const float4*)(wrelu + w * WRS + k);
          acc[w] = fmaf(x.x, wv0, fmaf(x.y, wv1, fmaf(x.z, wv2, fmaf(x.w, wv3, acc[w]))));
        }
      }
#pragma unroll
      for (int k = 148; k < 150; ++k) {
        float wv = w1p[(size_t)k * 150];
#pragma unroll
        for (int w = 0; w < 9; ++w) acc[w] = fmaf(wrelu[w * WRS + k], wv, acc[w]);
      }
#pragma unroll
      for (int w = 0; w < 9; ++w) wwl[w * RS + j] = acc[w];
    }
  }
  __syncthreads();

  // ---- P2: reduce partials -> swl/ewl ; w23 = W2@W3 ; b23 ----
  if (t < 900) {
#pragma unroll
    for (int p = 0; p < 3; ++p) {
      const int i = t + p * 900;          // pbuf addr = kc*2700 + i
      float v = pbuf[i] + pbuf[2700 + i] + pbuf[5400 + i];
      const int col = i / 9, s = i - 9 * col;
      const int half = col / 150, j = col - 150 * half;
      (half ? ewl : swl)[s * RS + j] = v;
    }
  } else {
    const int tw = t - 900;
    if (tw < 9) {
      float a = b3[tw];
      for (int m = 0; m < 150; ++m) a = fmaf(b2[m], w3l[m * 9 + tw], a);
      b23l[tw] = a;
    }
    for (int j = tw; j < 150; j += 124) {
      const float2* w2p = (const float2*)(W2 + (size_t)j * 150);
      float acc[9];
#pragma unroll
      for (int l = 0; l < 9; ++l) acc[l] = 0.f;
#pragma unroll 5
      for (int m = 0; m < 75; ++m) {
        float2 v = w2p[m];
#pragma unroll
        for (int l = 0; l < 9; ++l)
          acc[l] = fmaf(v.x, w3l[(2 * m) * 9 + l],
                        fmaf(v.y, w3l[(2 * m + 1) * 9 + l], acc[l]));
      }
#pragma unroll
      for (int l = 0; l < 9; ++l) w23l[j * 12 + l] = acc[l];
    }
  }
  __syncthreads();

  // ---- P3: 729 combos -> global ctab (layout identical to old stageB) ----
  if (t < 729) {
    const int s = t / 81, r0 = t - 81 * s, e = r0 / 9, w = r0 - 9 * e;
    const float* Ap = swl + s * RS;
    const float* Bp = ewl + e * RS;
    const float* Cp = wwl + w * RS;

    float acc[9];
#pragma unroll
    for (int l = 0; l < 9; ++l) acc[l] = b23l[l];

    for (int j = 0; j < 148; j += 4) {
      float4 a = *(const float4*)(Ap + j);
      float4 d = *(const float4*)(Bp + j);
      float4 cc = *(const float4*)(Cp + j);
      float h[4];
      h[0] = fmaxf(a.x + d.x + cc.x, 0.f);
      h[1] = fmaxf(a.y + d.y + cc.y, 0.f);
      h[2] = fmaxf(a.z + d.z + cc.z, 0.f);
      h[3] = fmaxf(a.w + d.w + cc.w, 0.f);
#pragma unroll
      for (int rr = 0; rr < 4; ++rr) {
        const float* wr = w23l + (j + rr) * 12;
        float4 wa = *(const float4*)(wr);
        float4 wb = *(const float4*)(wr + 4);
        float wc = wr[8];
        float p = h[rr];
        acc[0] = fmaf(p, wa.x, acc[0]);
        acc[1] = fmaf(p, wa.y, acc[1]);
        acc[2] = fmaf(p, wa.z, acc[2]);
        acc[3] = fmaf(p, wa.w, acc[3]);
        acc[4] = fmaf(p, wb.x, acc[4]);
        acc[5] = fmaf(p, wb.y, acc[5]);
        acc[6] = fmaf(p, wb.z, acc[6]);
        acc[7] = fmaf(p, wb.w, acc[7]);
        acc[8] = fmaf(p, wc, acc[8]);
      }
    }
#pragma unroll
    for (int j = 148; j < 150; ++j) {
      float p = fmaxf(Ap[j] + Bp[j] + Cp[j], 0.f);
      const float* wr = w23l + j * 12;
#pragma unroll
      for (int l = 0; l < 9; ++l) acc[l] = fmaf(p, wr[l], acc[l]);
    }

    float m = acc[0];
#pragma unroll
    for (int l = 1; l < 9; ++l) m = fmaxf(m, acc[l]);
    float ssum = 0.f;
#pragma unroll
    for (int l = 0; l < 9; ++l) ssum += __expf(acc[l] - m);
    const float lse = m + __logf(ssum);

    float* op = ctab + (size_t)(b * 729 + t) * 12;
    *(float4*)(op) = make_float4(acc[0], acc[1], acc[2], acc[3]);
    *(float4*)(op + 4) = make_float4(acc[4], acc[5], acc[6], acc[7]);
    *(float2*)(op + 8) = make_float2(acc[8], lse);
  }
}

// ---------------------------------------------------------------------------
// stageC: unchanged from the measured-best version (128 blocks x 256 threads;
// block = 1024 spans, thread = 4 consecutive spans, aligned float4 stores).
// ---------------------------------------------------------------------------
__global__ __launch_bounds__(256) void stageC(
    const float* __restrict__ ctab, const int* __restrict__ spans,
    const int* __restrict__ mask, const int* __restrict__ label,
    float* __restrict__ out)
{
  __shared__ __align__(16) float ctl[729 * 12];
  __shared__ float red[4];
  const int t = threadIdx.x, blk = blockIdx.x;
  const int b = blk >> 2;  // 4 blocks per batch

  const float4* src = (const float4*)(ctab + (size_t)b * 729 * 12);
  float4* dst = (float4*)ctl;
  for (int i = t; i < 2187; i += 256) dst[i] = src[i];
  __syncthreads();

  const int i0 = blk * 1024 + t * 4;
  const int4* sp = (const int4*)(spans + (size_t)3 * i0);
  const int4 sp0 = sp[0], sp1 = sp[1], sp2 = sp[2];
  const int4 mk = *(const int4*)(mask + i0);
  const int4 lb = *(const int4*)(label + i0);
  const int ss[4] = {sp0.x, sp0.w, sp1.z, sp2.y};
  const int ee[4] = {sp0.y, sp1.x, sp1.w, sp2.z};
  const int wws[4] = {sp0.z, sp1.y, sp2.x, sp2.w};
  const int mks[4] = {mk.x, mk.y, mk.z, mk.w};
  const int lbs[4] = {lb.x, lb.y, lb.z, lb.w};

  float buf[36];
  float loss = 0.f;
#pragma unroll
  for (int u = 0; u < 4; ++u) {
    const int s = min(max(ss[u], 0), 8);
    const int e = min(max(ee[u], 0), 8);
    const int w = min(max(wws[u], 0), 8);
    const int base = ((s * 9 + e) * 9 + w) * 12;
    const float4 v0 = *(const float4*)&ctl[base];
    const float4 v1 = *(const float4*)&ctl[base + 4];
    const float2 v2 = *(const float2*)&ctl[base + 8];
    buf[u * 9 + 0] = v0.x; buf[u * 9 + 1] = v0.y; buf[u * 9 + 2] = v0.z;
    buf[u * 9 + 3] = v0.w; buf[u * 9 + 4] = v1.x; buf[u * 9 + 5] = v1.y;
    buf[u * 9 + 6] = v1.z; buf[u * 9 + 7] = v1.w; buf[u * 9 + 8] = v2.x;
    if (mks[u] == 1) {
      const int l = min(max(lbs[u], 0), 8);
      float p = v0.x;
      p = (l == 1) ? v0.y : p;
      p = (l == 2) ? v0.z : p;
      p = (l == 3) ? v0.w : p;
      p = (l == 4) ? v1.x : p;
      p = (l == 5) ? v1.y : p;
      p = (l == 6) ? v1.z : p;
      p = (l == 7) ? v1.w : p;
      p = (l == 8) ? v2.x : p;
      loss += v2.y - p;  // lse - picked
    }
  }
  float4* op = (float4*)(out + (size_t)i0 * 9);
#pragma unroll
  for (int r = 0; r < 9; ++r)
    op[r] = make_float4(buf[4 * r], buf[4 * r + 1], buf[4 * r + 2], buf[4 * r + 3]);

#pragma unroll
  for (int off = 32; off > 0; off >>= 1) loss += __shfl_down(loss, off);
  if ((t & 63) == 0) red[t >> 6] = loss;
  __syncthreads();
  if (t == 0) atomicAdd(out + LOGITS_N, (red[0] + red[1]) + (red[2] + red[3]));
}

// ---------------------------------------------------------------------------
extern "C" void kernel_launch(void* const* d_in, const int* in_sizes, int n_in,
                              void* d_out, int out_size, void* d_ws, size_t ws_size,
                              hipStream_t stream) {
  const float* seq  = (const float*)d_in[0];
  const float* wtab = (const float*)d_in[1];
  const float* W1   = (const float*)d_in[2];
  const float* b1   = (const float*)d_in[3];
  const float* W2   = (const float*)d_in[4];
  const float* b2   = (const float*)d_in[5];
  const float* W3   = (const float*)d_in[6];
  const float* b3   = (const float*)d_in[7];
  const int* spans  = (const int*)d_in[8];
  const int* mask   = (const int*)d_in[9];
  const int* label  = (const int*)d_in[10];
  float* out = (float*)d_out;
  float* ws  = (float*)d_ws;
  (void)in_sizes; (void)n_in; (void)out_size; (void)ws_size;

  // ws layout (floats): ctab[32*729*12] only — part[] roundtrip eliminated
  float* ctab = ws;

  fusedAB<<<32, 1024, 0, stream>>>(seq, wtab, W1, b1, W2, b2, W3, b3, ctab, out);
  stageC<<<128, 256, 0, stream>>>(ctab, spans, mask, label, out);
}

// Round 2
// 166.026 us; speedup vs baseline: 1.0549x; 1.0549x over previous
//
#include <hip/hip_runtime.h>
#include <math.h>

// Problem constants (fixed by setup_inputs)
#define NB 32
#define SEQ 512
#define HD 768
#define NL 9
#define NSPAN (NB * 4096)
#define LOGITS_N (NSPAN * NL)     // 1179648
#define NJ 10                     // j-slices per batch
#define JW 15                     // hidden columns per slice (150/NJ)
#define WRS 152                   // padded row stride for relu'd width table

// ---------------------------------------------------------------------------
// fusedJ: grid = 32 batches x 10 j-slices = 320 blocks, 512 threads.
// Decomposes the hidden dim j (NOT k) across blocks, so each block runs the
// FULL K=768 reduction for its 15 columns and emits a complete 729-combo
// partial-logit table for its slice — zero cross-block deps inside the
// kernel. 512 thr x 320 blk = 2560 waves fully resident (2 blocks/CU at
// ~51 KB LDS), vs R1's 32-block / 5%-occupancy fusedAB.
// Phases (barrier-separated):
//   P0: stage relu(seq rows 0..8) (27.6 KB), relu(width_table), W3
//   P1: 240 thr: seq@W1 slice (8 k-chunks x 96);
//       135 thr: width@W1+b1 (full k);  135 thr: w23 slice = W2@W3 (full m)
//   P2: 270 thr: reduce k-chunk partials -> swl/ewl;  blk0: b23 -> global
//   P3: 729 combos (c, c+512): partial logits -> part2[b][sl][729][12]
// ---------------------------------------------------------------------------
__global__ __launch_bounds__(512) void fusedJ(
    const float* __restrict__ seq, const float* __restrict__ wtab,
    const float* __restrict__ W1, const float* __restrict__ b1,
    const float* __restrict__ W2, const float* __restrict__ b2,
    const float* __restrict__ W3, const float* __restrict__ b3,
    float* __restrict__ part2, float* __restrict__ b23g,
    float* __restrict__ out)
{
  __shared__ __align__(16) float xr[9 * HD];       // 6912 relu'd seq rows
  __shared__ __align__(16) float wrelu[9 * WRS];   // relu'd width table
  __shared__ __align__(16) float w3l[1350];        // W3 copy
  __shared__ __align__(16) float pbuf[240 * 9];    // k-chunk partials
  __shared__ __align__(16) float swl[9 * 16];      // [s][jj]
  __shared__ __align__(16) float ewl[9 * 16];
  __shared__ __align__(16) float wwl[9 * 16];
  __shared__ __align__(16) float w23s[JW * 12];    // (W2@W3) slice [jj][l]

  const int t = threadIdx.x, blk = blockIdx.x;
  const int b = blk / NJ, sl = blk - NJ * b;
  const int j0 = sl * JW;
  if (blk == 0 && t == 0) out[LOGITS_N] = 0.f;  // loss slot (stageC adds)

  // ---- P0: stage inputs ----
  {
    const float4* s4 = (const float4*)(seq + (size_t)b * SEQ * HD);
    float4* x4 = (float4*)xr;
    for (int i = t; i < 9 * HD / 4; i += 512) {
      float4 v = s4[i];
      x4[i] = make_float4(fmaxf(v.x, 0.f), fmaxf(v.y, 0.f),
                          fmaxf(v.z, 0.f), fmaxf(v.w, 0.f));
    }
    for (int i = t; i < 1350; i += 512) {
      int w = i / 150, k = i - 150 * w;
      wrelu[w * WRS + k] = fmaxf(wtab[i], 0.f);
      w3l[i] = W3[i];
    }
  }
  __syncthreads();

  // ---- P1 ----
  if (t < 240) {
    // seq@W1: t = kc*30 + half*15 + jj ; kc owns 96 k
    const int kc = t / 30, r = t - kc * 30, half = r / 15, jj = r - 15 * half;
    const float* w1p = W1 + (size_t)(half * HD + kc * 96) * 150 + j0 + jj;
    const float* xk = xr + kc * 96;
    float acc[9];
#pragma unroll
    for (int s = 0; s < 9; ++s) acc[s] = 0.f;
    for (int k = 0; k < 96; k += 4) {
      float wv0 = w1p[(k + 0) * 150];
      float wv1 = w1p[(k + 1) * 150];
      float wv2 = w1p[(k + 2) * 150];
      float wv3 = w1p[(k + 3) * 150];
#pragma unroll
      for (int s = 0; s < 9; ++s) {
        float4 x = *(const float4*)(xk + s * HD + k);  // broadcast-friendly
        acc[s] = fmaf(x.x, wv0, fmaf(x.y, wv1, fmaf(x.z, wv2, fmaf(x.w, wv3, acc[s]))));
      }
    }
    float* pp = pbuf + t * 9;
#pragma unroll
    for (int s = 0; s < 9; ++s) pp[s] = acc[s];
  } else if (t < 375) {
    // width@W1 + b1: (jj, w) pair, full 150-k sum
    const int idx = t - 240, jj = idx / 9, w = idx - 9 * jj;
    const float* w1p = W1 + (size_t)1536 * 150 + j0 + jj;
    const float* wr = wrelu + w * WRS;
    float a = b1[j0 + jj];
#pragma unroll 2
    for (int k = 0; k < 150; k += 2) {
      a = fmaf(wr[k], w1p[(k + 0) * 150], a);
      a = fmaf(wr[k + 1], w1p[(k + 1) * 150], a);
    }
    wwl[w * 16 + jj] = a;
  } else if (t < 510) {
    // w23 slice: (jj, l) pair, full 150-m sum
    const int idx = t - 375, jj = idx / 9, l = idx - 9 * jj;
    const float* w2p = W2 + (size_t)(j0 + jj) * 150;
    float a = 0.f;
#pragma unroll 2
    for (int m = 0; m < 150; ++m) a = fmaf(w2p[m], w3l[m * 9 + l], a);
    w23s[jj * 12 + l] = a;
  }
  __syncthreads();

  // ---- P2: reduce k-chunk partials ; blk 0 computes b23 ----
  if (t < 270) {
    const int jj = t / 18, r = t - 18 * jj, half = r / 9, s = r - 9 * half;
    float v = 0.f;
#pragma unroll
    for (int kc = 0; kc < 8; ++kc) v += pbuf[(kc * 30 + half * 15 + jj) * 9 + s];
    (half ? ewl : swl)[s * 16 + jj] = v;
  } else if (blk == 0 && t < 279) {
    const int l = t - 270;
    float a = b3[l];
    for (int m = 0; m < 150; ++m) a = fmaf(b2[m], w3l[m * 9 + l], a);
    b23g[l] = a;
  }
  __syncthreads();

  // ---- P3: 729 combo partials for this slice ----
  for (int c = t; c < 729; c += 512) {
    const int s = c / 81, r0 = c - 81 * s, e = r0 / 9, w = r0 - 9 * e;
    float acc[9];
#pragma unroll
    for (int l = 0; l < 9; ++l) acc[l] = 0.f;
#pragma unroll
    for (int jj = 0; jj < JW; ++jj) {
      float h = fmaxf(swl[s * 16 + jj] + ewl[e * 16 + jj] + wwl[w * 16 + jj], 0.f);
      const float* wr = w23s + jj * 12;
      float4 wa = *(const float4*)(wr);
      float4 wb = *(const float4*)(wr + 4);
      float wc = wr[8];
      acc[0] = fmaf(h, wa.x, acc[0]);
      acc[1] = fmaf(h, wa.y, acc[1]);
      acc[2] = fmaf(h, wa.z, acc[2]);
      acc[3] = fmaf(h, wa.w, acc[3]);
      acc[4] = fmaf(h, wb.x, acc[4]);
      acc[5] = fmaf(h, wb.y, acc[5]);
      acc[6] = fmaf(h, wb.z, acc[6]);
      acc[7] = fmaf(h, wb.w, acc[7]);
      acc[8] = fmaf(h, wc, acc[8]);
    }
    float* op = part2 + ((size_t)(b * NJ + sl) * 729 + c) * 12;
    *(float4*)(op) = make_float4(acc[0], acc[1], acc[2], acc[3]);
    *(float4*)(op + 4) = make_float4(acc[4], acc[5], acc[6], acc[7]);
    *(float4*)(op + 8) = make_float4(acc[8], 0.f, 0.f, 0.f);
  }
}

// ---------------------------------------------------------------------------
// stageC: measured-best gather structure (128 blocks x 256 threads, block =
// 1024 spans, thread = 4 consecutive spans). Staging loop now folds the
// NJ slice-partials + b23; lse computed in LDS before the gather.
// ---------------------------------------------------------------------------
__global__ __launch_bounds__(256) void stageC(
    const float* __restrict__ part2, const float* __restrict__ b23g,
    const int* __restrict__ spans, const int* __restrict__ mask,
    const int* __restrict__ label, float* __restrict__ out)
{
  __shared__ __align__(16) float ctl[729 * 12];
  __shared__ __align__(16) float b23s[12];
  __shared__ float red[4];
  const int t = threadIdx.x, blk = blockIdx.x;
  const int b = blk >> 2;  // 4 blocks per batch

  if (t < 12) b23s[t] = (t < 9) ? b23g[t] : 0.f;
  __syncthreads();

  const float4* p4 = (const float4*)part2 + (size_t)b * NJ * 2187;
  const float4* bq = (const float4*)b23s;
  float4* dst = (float4*)ctl;
  for (int i = t; i < 2187; i += 256) {
    float4 a = bq[i % 3];
#pragma unroll
    for (int s2 = 0; s2 < NJ; ++s2) {
      float4 v = p4[s2 * 2187 + i];
      a.x += v.x; a.y += v.y; a.z += v.z; a.w += v.w;
    }
    dst[i] = a;
  }
  __syncthreads();

  for (int c = t; c < 729; c += 256) {
    const float* row = ctl + c * 12;
    float m = row[0];
#pragma unroll
    for (int l = 1; l < 9; ++l) m = fmaxf(m, row[l]);
    float ssum = 0.f;
#pragma unroll
    for (int l = 0; l < 9; ++l) ssum += __expf(row[l] - m);
    ctl[c * 12 + 9] = m + __logf(ssum);
  }
  __syncthreads();

  const int i0 = blk * 1024 + t * 4;
  const int4* sp = (const int4*)(spans + (size_t)3 * i0);
  const int4 sp0 = sp[0], sp1 = sp[1], sp2 = sp[2];
  const int4 mk = *(const int4*)(mask + i0);
  const int4 lb = *(const int4*)(label + i0);
  const int ss[4] = {sp0.x, sp0.w, sp1.z, sp2.y};
  const int ee[4] = {sp0.y, sp1.x, sp1.w, sp2.z};
  const int wws[4] = {sp0.z, sp1.y, sp2.x, sp2.w};
  const int mks[4] = {mk.x, mk.y, mk.z, mk.w};
  const int lbs[4] = {lb.x, lb.y, lb.z, lb.w};

  float buf[36];
  float loss = 0.f;
#pragma unroll
  for (int u = 0; u < 4; ++u) {
    const int s = min(max(ss[u], 0), 8);
    const int e = min(max(ee[u], 0), 8);
    const int w = min(max(wws[u], 0), 8);
    const int base = ((s * 9 + e) * 9 + w) * 12;
    const float4 v0 = *(const float4*)&ctl[base];
    const float4 v1 = *(const float4*)&ctl[base + 4];
    const float2 v2 = *(const float2*)&ctl[base + 8];
    buf[u * 9 + 0] = v0.x; buf[u * 9 + 1] = v0.y; buf[u * 9 + 2] = v0.z;
    buf[u * 9 + 3] = v0.w; buf[u * 9 + 4] = v1.x; buf[u * 9 + 5] = v1.y;
    buf[u * 9 + 6] = v1.z; buf[u * 9 + 7] = v1.w; buf[u * 9 + 8] = v2.x;
    if (mks[u] == 1) {
      const int l = min(max(lbs[u], 0), 8);
      float p = v0.x;
      p = (l == 1) ? v0.y : p;
      p = (l == 2) ? v0.z : p;
      p = (l == 3) ? v0.w : p;
      p = (l == 4) ? v1.x : p;
      p = (l == 5) ? v1.y : p;
      p = (l == 6) ? v1.z : p;
      p = (l == 7) ? v1.w : p;
      p = (l == 8) ? v2.x : p;
      loss += v2.y - p;  // lse - picked
    }
  }
  float4* op = (float4*)(out + (size_t)i0 * 9);
#pragma unroll
  for (int r = 0; r < 9; ++r)
    op[r] = make_float4(buf[4 * r], buf[4 * r + 1], buf[4 * r + 2], buf[4 * r + 3]);

#pragma unroll
  for (int off = 32; off > 0; off >>= 1) loss += __shfl_down(loss, off);
  if ((t & 63) == 0) red[t >> 6] = loss;
  __syncthreads();
  if (t == 0) atomicAdd(out + LOGITS_N, (red[0] + red[1]) + (red[2] + red[3]));
}

// ---------------------------------------------------------------------------
extern "C" void kernel_launch(void* const* d_in, const int* in_sizes, int n_in,
                              void* d_out, int out_size, void* d_ws, size_t ws_size,
                              hipStream_t stream) {
  const float* seq  = (const float*)d_in[0];
  const float* wtab = (const float*)d_in[1];
  const float* W1   = (const float*)d_in[2];
  const float* b1   = (const float*)d_in[3];
  const float* W2   = (const float*)d_in[4];
  const float* b2   = (const float*)d_in[5];
  const float* W3   = (const float*)d_in[6];
  const float* b3   = (const float*)d_in[7];
  const int* spans  = (const int*)d_in[8];
  const int* mask   = (const int*)d_in[9];
  const int* label  = (const int*)d_in[10];
  float* out = (float*)d_out;
  float* ws  = (float*)d_ws;
  (void)in_sizes; (void)n_in; (void)out_size; (void)ws_size;

  // ws layout (floats): part2[32*10*729*12] = 2,799,360 | b23g[16]
  float* part2 = ws;
  float* b23g  = ws + (size_t)NB * NJ * 729 * 12;

  fusedJ<<<NB * NJ, 512, 0, stream>>>(seq, wtab, W1, b1, W2, b2, W3, b3,
                                      part2, b23g, out);
  stageC<<<128, 256, 0, stream>>>(part2, b23g, spans, mask, label, out);
}

// Round 3
// 134.441 us; speedup vs baseline: 1.3028x; 1.2349x over previous
//
#include <hip/hip_runtime.h>
#include <math.h>

// Problem constants (fixed by setup_inputs)
#define NB 32
#define SEQ 512
#define HD 768
#define NL 9
#define NSPAN (NB * 4096)
#define LOGITS_N (NSPAN * NL)     // 1179648
#define RS 156                    // padded LDS row stride for 9x150 tables
#define CH 16                     // k-chunks per batch in stageA
#define CK 48                     // 768 / CH

// ---------------------------------------------------------------------------
// stageA: grid = 32*CH + 15 blocks, 320 threads.  (R0 verbatim — measured
// best projection pipeline; both fusion attempts lost to it.)
// ---------------------------------------------------------------------------
__global__ __launch_bounds__(320) void stageA(
    const float* __restrict__ seq, const float* __restrict__ wtab,
    const float* __restrict__ W1, const float* __restrict__ b1,
    const float* __restrict__ W2, const float* __restrict__ b2,
    const float* __restrict__ W3, const float* __restrict__ b3,
    float* __restrict__ part, float* __restrict__ wwt,
    float* __restrict__ w23p, float* __restrict__ b23p,
    float* __restrict__ out)
{
  const int gid = blockIdx.x, t = threadIdx.x;

  if (gid < 32 * CH) {
    __shared__ __align__(16) float xr[9 * CK];
    const int b = gid / CH, chunk = gid - b * CH;
    const float* sb = seq + (size_t)b * SEQ * HD + chunk * CK;
    for (int i = t; i < 9 * CK; i += 320) {
      int s = i / CK, k = i - s * CK;
      xr[i] = fmaxf(sb[(size_t)s * HD + k], 0.f);
    }
    __syncthreads();
    if (t < 300) {
      const int half = t / 150, j = t - 150 * half;
      float acc[9];
#pragma unroll
      for (int s = 0; s < 9; ++s) acc[s] = 0.f;
      const float* w1p = W1 + (size_t)(half * 768 + chunk * CK) * 150 + j;
      for (int k = 0; k < CK; k += 4) {
        float wv0 = w1p[(size_t)(k + 0) * 150];
        float wv1 = w1p[(size_t)(k + 1) * 150];
        float wv2 = w1p[(size_t)(k + 2) * 150];
        float wv3 = w1p[(size_t)(k + 3) * 150];
#pragma unroll
        for (int s = 0; s < 9; ++s) {
          const float4 x = *(const float4*)&xr[s * CK + k];
          acc[s] = fmaf(x.x, wv0, fmaf(x.y, wv1, fmaf(x.z, wv2, fmaf(x.w, wv3, acc[s]))));
        }
      }
      float* op = part + ((size_t)gid * 2 + half) * 1350 + j;
#pragma unroll
      for (int s = 0; s < 9; ++s) op[s * 150] = acc[s];
    }
  } else if (gid < 32 * CH + 9) {
    __shared__ float xw[152];
    const int w = gid - 32 * CH;
    for (int i = t; i < 150; i += 320) xw[i] = fmaxf(wtab[w * 150 + i], 0.f);
    __syncthreads();
    if (t < 150) {
      const int j = t;
      float a = b1[j];
      const float* wp = W1 + (size_t)1536 * 150 + j;
#pragma unroll 3
      for (int k = 0; k < 150; k += 2) {
        a = fmaf(xw[k], wp[(size_t)k * 150], a);
        a = fmaf(xw[k + 1], wp[(size_t)(k + 1) * 150], a);
      }
      wwt[w * 150 + j] = a;
    }
  } else {
    __shared__ float w3l[1350];
    const int o = (gid - 32 * CH - 9) * 320 + t;
    for (int i = t; i < 1350; i += 320) w3l[i] = W3[i];
    __syncthreads();
    if (o < 1350) {
      const int j = o / 9, l = o - 9 * j;
      const float2* w2p = (const float2*)(W2 + (size_t)j * 150);
      float a = 0.f;
#pragma unroll 5
      for (int m = 0; m < 75; ++m) {
        float2 v = w2p[m];
        a = fmaf(v.x, w3l[(2 * m) * 9 + l], a);
        a = fmaf(v.y, w3l[(2 * m + 1) * 9 + l], a);
      }
      w23p[j * 12 + l] = a;
    } else if (o < 1359) {
      const int l = o - 1350;
      float a = b3[l];
#pragma unroll 5
      for (int m = 0; m < 150; ++m) a = fmaf(b2[m], w3l[m * 9 + l], a);
      b23p[l] = a;
    }
    if (gid == 32 * CH + 9 && t == 0) out[LOGITS_N] = 0.f;  // loss slot
  }
}

// ---------------------------------------------------------------------------
// stageB: grid = 192 blocks x 256 threads (R0 verbatim). Produces ctab rows
// [acc0..acc8, lse, pad, pad] per (batch, combo).
// ---------------------------------------------------------------------------
__global__ __launch_bounds__(256) void stageB(
    const float* __restrict__ part, const float* __restrict__ wwt,
    const float* __restrict__ w23p, const float* __restrict__ b23p,
    float* __restrict__ ctab)
{
  __shared__ __align__(16) float swl[9 * RS];
  __shared__ __align__(16) float ewl[9 * RS];
  __shared__ __align__(16) float wwl[9 * RS];
  __shared__ __align__(16) float w23l[1800];
  __shared__ float b23l[12];

  const int t = threadIdx.x, blk = blockIdx.x;
  const int b = blk / 6, q = blk - 6 * b;
  const float* pb = part + (size_t)b * CH * 2700;
  for (int o = t; o < 1350; o += 256) {
    float vs = 0.f, ve = 0.f;
#pragma unroll
    for (int c2 = 0; c2 < CH; ++c2) {
      vs += pb[c2 * 2700 + o];
      ve += pb[c2 * 2700 + 1350 + o];
    }
    const int s = o / 150, j = o - 150 * s;
    swl[s * RS + j] = vs;
    ewl[s * RS + j] = ve;
    wwl[s * RS + j] = wwt[o];
  }
  for (int o = t; o < 1800; o += 256) w23l[o] = w23p[o];
  if (t < 9) b23l[t] = b23p[t];
  __syncthreads();

  const int c = q * 128 + t;
  if (t >= 128 || c >= 729) return;
  const int s = c / 81, r0 = c - 81 * s, e = r0 / 9, w = r0 - 9 * e;
  const float* Ap = swl + s * RS;
  const float* Bp = ewl + e * RS;
  const float* Cp = wwl + w * RS;

  float acc[9];
#pragma unroll
  for (int l = 0; l < 9; ++l) acc[l] = b23l[l];

  for (int j = 0; j < 148; j += 4) {
    float4 a = *(const float4*)(Ap + j);
    float4 d = *(const float4*)(Bp + j);
    float4 cc = *(const float4*)(Cp + j);
    float h[4];
    h[0] = fmaxf(a.x + d.x + cc.x, 0.f);
    h[1] = fmaxf(a.y + d.y + cc.y, 0.f);
    h[2] = fmaxf(a.z + d.z + cc.z, 0.f);
    h[3] = fmaxf(a.w + d.w + cc.w, 0.f);
#pragma unroll
    for (int rr = 0; rr < 4; ++rr) {
      const float* wr = w23l + (j + rr) * 12;
      float4 wa = *(const float4*)(wr);
      float4 wb = *(const float4*)(wr + 4);
      float wc = wr[8];
      float p = h[rr];
      acc[0] = fmaf(p, wa.x, acc[0]);
      acc[1] = fmaf(p, wa.y, acc[1]);
      acc[2] = fmaf(p, wa.z, acc[2]);
      acc[3] = fmaf(p, wa.w, acc[3]);
      acc[4] = fmaf(p, wb.x, acc[4]);
      acc[5] = fmaf(p, wb.y, acc[5]);
      acc[6] = fmaf(p, wb.z, acc[6]);
      acc[7] = fmaf(p, wb.w, acc[7]);
      acc[8] = fmaf(p, wc, acc[8]);
    }
  }
#pragma unroll
  for (int j = 148; j < 150; ++j) {
    float p = fmaxf(Ap[j] + Bp[j] + Cp[j], 0.f);
    const float* wr = w23l + j * 12;
#pragma unroll
    for (int l = 0; l < 9; ++l) acc[l] = fmaf(p, wr[l], acc[l]);
  }

  float m = acc[0];
#pragma unroll
  for (int l = 1; l < 9; ++l) m = fmaxf(m, acc[l]);
  float ssum = 0.f;
#pragma unroll
  for (int l = 0; l < 9; ++l) ssum += __expf(acc[l] - m);
  const float lse = m + __logf(ssum);

  float* op = ctab + (size_t)(b * 729 + c) * 12;
  *(float4*)(op) = make_float4(acc[0], acc[1], acc[2], acc[3]);
  *(float4*)(op + 4) = make_float4(acc[4], acc[5], acc[6], acc[7]);
  *(float2*)(op + 8) = make_float2(acc[8], lse);
}

// ---------------------------------------------------------------------------
// stageCs: NEW streaming gather. 512 blocks x 256 threads, 1 span/thread
// (131072 threads = 8 waves/CU vs old 128-block version's 0.5 block/CU).
// No LDS staging — ctab is 1.1 MB, L2-resident; 3 random L2 float4 reads
// per span. Scalar output stores (36 B/span base is not 16B-aligned);
// stores are fire-and-forget, write traffic is only 4.7 MB.
// ---------------------------------------------------------------------------
__global__ __launch_bounds__(256) void stageCs(
    const float* __restrict__ ctab, const int* __restrict__ spans,
    const int* __restrict__ mask, const int* __restrict__ label,
    float* __restrict__ out)
{
  __shared__ float red[4];
  const int t = threadIdx.x;
  const int i = blockIdx.x * 256 + t;   // span id, 0..131071
  const int b = i >> 12;                // batch

  const int s3 = i * 3;
  int s = spans[s3], e = spans[s3 + 1], w = spans[s3 + 2];
  s = min(max(s, 0), 8);
  e = min(max(e, 0), 8);
  w = min(max(w, 0), 8);

  const float* row = ctab + ((size_t)b * 729 + (s * 9 + e) * 9 + w) * 12;
  const float4 v0 = *(const float4*)(row);
  const float4 v1 = *(const float4*)(row + 4);
  const float2 v2 = *(const float2*)(row + 8);

  float* op = out + (size_t)i * 9;
  op[0] = v0.x; op[1] = v0.y; op[2] = v0.z; op[3] = v0.w;
  op[4] = v1.x; op[5] = v1.y; op[6] = v1.z; op[7] = v1.w;
  op[8] = v2.x;

  float loss = 0.f;
  if (mask[i] == 1) {
    const int l = min(max(label[i], 0), 8);
    float p = v0.x;
    p = (l == 1) ? v0.y : p;
    p = (l == 2) ? v0.z : p;
    p = (l == 3) ? v0.w : p;
    p = (l == 4) ? v1.x : p;
    p = (l == 5) ? v1.y : p;
    p = (l == 6) ? v1.z : p;
    p = (l == 7) ? v1.w : p;
    p = (l == 8) ? v2.x : p;
    loss = v2.y - p;  // lse - picked
  }

#pragma unroll
  for (int off = 32; off > 0; off >>= 1) loss += __shfl_down(loss, off);
  if ((t & 63) == 0) red[t >> 6] = loss;
  __syncthreads();
  if (t == 0) atomicAdd(out + LOGITS_N, (red[0] + red[1]) + (red[2] + red[3]));
}

// ---------------------------------------------------------------------------
extern "C" void kernel_launch(void* const* d_in, const int* in_sizes, int n_in,
                              void* d_out, int out_size, void* d_ws, size_t ws_size,
                              hipStream_t stream) {
  const float* seq  = (const float*)d_in[0];
  const float* wtab = (const float*)d_in[1];
  const float* W1   = (const float*)d_in[2];
  const float* b1   = (const float*)d_in[3];
  const float* W2   = (const float*)d_in[4];
  const float* b2   = (const float*)d_in[5];
  const float* W3   = (const float*)d_in[6];
  const float* b3   = (const float*)d_in[7];
  const int* spans  = (const int*)d_in[8];
  const int* mask   = (const int*)d_in[9];
  const int* label  = (const int*)d_in[10];
  float* out = (float*)d_out;
  float* ws  = (float*)d_ws;
  (void)in_sizes; (void)n_in; (void)out_size; (void)ws_size;

  // ws layout (floats): part[32*16*2700] | wwt[1352] | w23[1800] | b23[16]
  //                     | ctab[32*729*12]
  float* part = ws;                                // 1,382,400 floats
  float* wwt  = ws + (size_t)32 * CH * 2700;       // 1352
  float* w23p = wwt + 1352;                        // 1800 (16B-aligned)
  float* b23p = w23p + 1800;                       // 16
  float* ctab = b23p + 16;                         // 279,936

  stageA<<<32 * CH + 15, 320, 0, stream>>>(seq, wtab, W1, b1, W2, b2, W3, b3,
                                           part, wwt, w23p, b23p, out);
  stageB<<<192, 256, 0, stream>>>(part, wwt, w23p, b23p, ctab);
  stageCs<<<NSPAN / 256, 256, 0, stream>>>(ctab, spans, mask, label, out);
}